// Round 15
// baseline (152.444 us; speedup 1.0000x reference)
//
#include <hip/hip_runtime.h>
#include <math.h>

#define NBATCH 2
#define CHN    64
#define NYY    80
#define NXX    80
#define NCLS   80
#define NPIX   6400      // 80*80
#define KTOT   512000    // NCLS*NPIX
#define NOUT   85        // 5 + NCLS
#define NBLK   500       // KTOT / 1024

typedef float vf4 __attribute__((ext_vector_type(4)));

// output = 87,040,000 floats = 21,760,000 float4 quads
#define QTOT   21760000L
#define QF1    10905600L     // conv1: 71 iters x 153600 (~50%)
#define QF2    16435200L     // conv2: 54 iters x 102400 (~25%)
#define QF3    20531200L     // flags: 4 iters x 1024000 (~19%)
                             // scatter: QF3..QTOT (2 x 1024000, guarded; ~6%)

// ============ K1: fused 3x3 conv + ReLU (hm fp64-acc | wh/reg fp32) ============
// grid 480 x 320 thr, 49,152 B LDS. bl%3==0 -> hm (fp64), else wr (fp32).
__global__ __launch_bounds__(320)
void conv1_kernel(const float* __restrict__ x,
                  const float* __restrict__ hw1, const float* __restrict__ hb1,
                  const float* __restrict__ ww1, const float* __restrict__ wb1,
                  const float* __restrict__ rw1, const float* __restrict__ rb1,
                  double* __restrict__ c1hm, float* __restrict__ c1wr,
                  vf4* __restrict__ outq)
{
    __shared__ double smem_d[6144];    // 49,152 B
    const int bl = blockIdx.x;
    const int t  = threadIdx.x;

    const int gtid = bl * 320 + t;
    const int nth  = 480 * 320;        // 153600
    const vf4 fz = {0.f, 0.f, 0.f, 0.f};

    const int pxq = t % 80;
    const int ocq = t / 80;            // 0..3
    const int r   = pxq / 20;          // row 0..3
    const int c   = (pxq % 20) * 4;    // col 0..76

    float* lxf = (float*)smem_d;       // [16][6][80] floats = 30,720 B

    if (bl % 3 == 0) {
        // ---------------- hm path: fp64 acc ----------------
        double* lwd = (double*)((char*)smem_d + 30720);  // [144][16] = 18,432 B

        const int idx = bl / 3;        // 0..159
        const int yt  = idx % 20;
        const int ocg = (idx / 20) % 4;
        const int b   = idx / 80;
        const int oc0 = ocg * 16 + ocq * 4;
        const int gy0 = yt * 4;

        const float* xin = x + (size_t)b * CHN * NPIX;

        double acc[4][4];
        #pragma unroll
        for (int j = 0; j < 4; j++)
            #pragma unroll
            for (int o = 0; o < 4; o++) acc[j][o] = (double)hb1[oc0 + o];

        for (int cc = 0; cc < 4; cc++) {
            const int icc = cc * 16;
            __syncthreads();
            for (int j = t; j < 1920; j += 320) {
                int ic_l = j / 120; int rem = j % 120;
                int row_l = rem / 20; int c4 = (rem % 20) * 4;
                int gy = gy0 - 1 + row_l;
                float4 v = make_float4(0.f, 0.f, 0.f, 0.f);
                if ((unsigned)gy < 80u)
                    v = *(const float4*)(xin + (size_t)(icc + ic_l) * NPIX + gy * NXX + c4);
                *(float4*)&lxf[(ic_l * 6 + row_l) * 80 + c4] = v;
            }
            for (int j = t; j < 2304; j += 320) {
                int oc_l = j % 16; int k = j / 16;
                int ic_l = k / 9, tap = k % 9;
                lwd[k * 16 + oc_l] =
                    (double)hw1[((size_t)(ocg * 16 + oc_l) * CHN + icc + ic_l) * 9 + tap];
            }
            __syncthreads();
            {   // zero-fill slice: 71 iters total, ~18/phase
                int i0 = cc * 18, i1 = (cc == 3) ? 71 : cc * 18 + 18;
                for (int i = i0; i < i1; i++) {
                    long q = (long)gtid + (long)i * nth;
                    if (q < QF1) __builtin_nontemporal_store(fz, outq + q);
                }
            }
            for (int ic = 0; ic < 16; ic++) {
                double xw[3][6];
                #pragma unroll
                for (int ky = 0; ky < 3; ky++) {
                    const float* row = &lxf[(ic * 6 + r + ky) * 80];
                    xw[ky][0] = (c > 0) ? (double)row[c - 1] : 0.0;
                    float4 m = *(const float4*)&row[c];
                    xw[ky][1] = (double)m.x; xw[ky][2] = (double)m.y;
                    xw[ky][3] = (double)m.z; xw[ky][4] = (double)m.w;
                    xw[ky][5] = (c < 76) ? (double)row[c + 4] : 0.0;
                }
                #pragma unroll
                for (int ky = 0; ky < 3; ky++)
                #pragma unroll
                for (int kx = 0; kx < 3; kx++) {
                    const double* wv = &lwd[(ic * 9 + ky * 3 + kx) * 16 + ocq * 4];
                    double w0 = wv[0], w1d = wv[1], w2 = wv[2], w3 = wv[3];
                    #pragma unroll
                    for (int j = 0; j < 4; j++) {
                        double xv = xw[ky][j + kx];
                        acc[j][0] += xv * w0; acc[j][1] += xv * w1d;
                        acc[j][2] += xv * w2; acc[j][3] += xv * w3;
                    }
                }
            }
        }
        size_t pix = (size_t)(gy0 + r) * NXX + c;
        #pragma unroll
        for (int o = 0; o < 4; o++) {
            double* dst = c1hm + ((size_t)b * CHN + oc0 + o) * NPIX + pix;
            double2 lo, hi;
            lo.x = acc[0][o] > 0.0 ? acc[0][o] : 0.0;
            lo.y = acc[1][o] > 0.0 ? acc[1][o] : 0.0;
            hi.x = acc[2][o] > 0.0 ? acc[2][o] : 0.0;
            hi.y = acc[3][o] > 0.0 ? acc[3][o] : 0.0;
            *(double2*)dst = lo;
            *(double2*)(dst + 2) = hi;
        }
    } else {
        // ---------------- wh/reg path: fp32 ----------------
        float* lwf = (float*)((char*)smem_d + 30720);    // [144][16] = 9,216 B

        const int idx = bl - bl / 3 - 1;   // 0..319
        const int yt  = idx % 20;
        const int ocg = (idx / 20) % 4;
        const int img = idx / 80;          // 0=wh b0, 1=wh b1, 2=reg b0, 3=reg b1

        const int head = img >> 1, b = img & 1;
        const float* w1 = (head == 0) ? ww1 : rw1;
        const float* b1 = (head == 0) ? wb1 : rb1;
        const float* xin = x + (size_t)b * CHN * NPIX;

        const int oc0 = ocg * 16 + ocq * 4;
        const int gy0 = yt * 4;

        float acc[4][4];
        #pragma unroll
        for (int j = 0; j < 4; j++)
            #pragma unroll
            for (int o = 0; o < 4; o++) acc[j][o] = b1[oc0 + o];

        for (int cc = 0; cc < 4; cc++) {
            const int icc = cc * 16;
            __syncthreads();
            for (int j = t; j < 1920; j += 320) {
                int ic_l = j / 120; int rem = j % 120;
                int row_l = rem / 20; int c4 = (rem % 20) * 4;
                int gy = gy0 - 1 + row_l;
                float4 v = make_float4(0.f, 0.f, 0.f, 0.f);
                if ((unsigned)gy < 80u)
                    v = *(const float4*)(xin + (size_t)(icc + ic_l) * NPIX + gy * NXX + c4);
                *(float4*)&lxf[(ic_l * 6 + row_l) * 80 + c4] = v;
            }
            for (int j = t; j < 2304; j += 320) {
                int oc_l = j % 16; int k = j / 16;
                int ic_l = k / 9, tap = k % 9;
                lwf[k * 16 + oc_l] =
                    w1[((size_t)(ocg * 16 + oc_l) * CHN + icc + ic_l) * 9 + tap];
            }
            __syncthreads();
            {
                int i0 = cc * 18, i1 = (cc == 3) ? 71 : cc * 18 + 18;
                for (int i = i0; i < i1; i++) {
                    long q = (long)gtid + (long)i * nth;
                    if (q < QF1) __builtin_nontemporal_store(fz, outq + q);
                }
            }
            for (int ic = 0; ic < 16; ic++) {
                float xw[3][6];
                #pragma unroll
                for (int ky = 0; ky < 3; ky++) {
                    const float* row = &lxf[(ic * 6 + r + ky) * 80];
                    xw[ky][0] = (c > 0) ? row[c - 1] : 0.f;
                    float4 m = *(const float4*)&row[c];
                    xw[ky][1] = m.x; xw[ky][2] = m.y;
                    xw[ky][3] = m.z; xw[ky][4] = m.w;
                    xw[ky][5] = (c < 76) ? row[c + 4] : 0.f;
                }
                #pragma unroll
                for (int ky = 0; ky < 3; ky++)
                #pragma unroll
                for (int kx = 0; kx < 3; kx++) {
                    const float* wv = &lwf[(ic * 9 + ky * 3 + kx) * 16 + ocq * 4];
                    float w0 = wv[0], w1v = wv[1], w2 = wv[2], w3 = wv[3];
                    #pragma unroll
                    for (int j = 0; j < 4; j++) {
                        float xv = xw[ky][j + kx];
                        acc[j][0] += xv * w0; acc[j][1] += xv * w1v;
                        acc[j][2] += xv * w2; acc[j][3] += xv * w3;
                    }
                }
            }
        }
        size_t pix = (size_t)(gy0 + r) * NXX + c;
        #pragma unroll
        for (int o = 0; o < 4; o++) {
            float4 v;
            v.x = fmaxf(acc[0][o], 0.f); v.y = fmaxf(acc[1][o], 0.f);
            v.z = fmaxf(acc[2][o], 0.f); v.w = fmaxf(acc[3][o], 0.f);
            *(float4*)(c1wr + ((size_t)img * CHN + oc0 + o) * NPIX + pix) = v;
        }
    }
}

// ============ K2: merged conv2_hm (fp64 logits, fetch-once) + conv2_wr ============
// grid 400 x 256 thr. bl<200: hm. bl>=200: wr.
__global__ __launch_bounds__(256)
void conv2_kernel(const double* __restrict__ c1hm,
                  const float* __restrict__ hm_w2, const float* __restrict__ hm_b2,
                  const float* __restrict__ c1wr,
                  const float* __restrict__ wh_w2, const float* __restrict__ wh_b2,
                  const float* __restrict__ rg_w2, const float* __restrict__ rg_b2,
                  double* __restrict__ hm_z, float* __restrict__ wh, float* __restrict__ rg,
                  vf4* __restrict__ outq)
{
    __shared__ double smem2[9216];     // 73,728 B (hm path only)
    const int bl = blockIdx.x;
    const int t  = threadIdx.x;

    // zero-fill slice (drains under compute)
    {
        const int gtid = bl * 256 + t;
        const vf4 fz = {0.f, 0.f, 0.f, 0.f};
        for (int i = 0; i < 54; i++) {
            long q = QF1 + (long)gtid + (long)i * 102400;
            if (q < QF2) __builtin_nontemporal_store(fz, outq + q);
        }
    }

    if (bl < 200) {
        double* lx = smem2;            // [64 ic][64 px] = 32,768 B
        double* lw = smem2 + 4096;     // [64 ic][80 oc] = 40,960 B

        const int b   = bl / 100;
        const int px0 = (bl % 100) * 64;

        const double* in = c1hm + (size_t)b * CHN * NPIX;
        for (int j = t; j < 4096; j += 256) {
            int ic = j >> 6, px = j & 63;
            lx[j] = in[(size_t)ic * NPIX + px0 + px];
        }
        for (int j = t; j < 5120; j += 256) {
            int ic = j / 80, oc = j % 80;
            lw[j] = (double)hm_w2[(size_t)oc * CHN + ic];
        }
        __syncthreads();

        const int px  = t & 63;
        const int ocg = t >> 6;        // 0..3 (wave-uniform -> broadcast reads)
        double acc[20];
        #pragma unroll
        for (int o = 0; o < 20; o++) acc[o] = (double)hm_b2[ocg * 20 + o];

        for (int ic = 0; ic < 64; ic++) {
            double xv = lx[ic * 64 + px];
            const double* wrow = &lw[ic * 80 + ocg * 20];
            #pragma unroll
            for (int o = 0; o < 20; o++) acc[o] += xv * wrow[o];
        }
        #pragma unroll
        for (int o = 0; o < 20; o++)
            hm_z[((size_t)b * NCLS + ocg * 20 + o) * NPIX + px0 + px] = acc[o];
    } else {
        const int blw  = bl - 200;
        const int chunk = blw % 25;
        const int hc   = (blw / 25) % 4;
        const int b    = blw / 100;
        const int head = hc >> 1, ch = hc & 1;

        const int p = chunk * 256 + t;
        const float* in = c1wr + ((size_t)(head * 2 + b) * CHN) * NPIX;
        const float* w  = (head == 0) ? wh_w2 + (size_t)ch * CHN : rg_w2 + (size_t)ch * CHN;
        float acc = (head == 0) ? wh_b2[ch] : rg_b2[ch];
        for (int ic = 0; ic < CHN; ic++) acc += in[(size_t)ic * NPIX + p] * w[ic];
        acc = fmaxf(acc, 0.f);
        float* o = (head == 0) ? wh : rg;
        o[((size_t)b * 2 + ch) * NPIX + p] = acc;
    }
}

// ============ K3: maxima flags on fp64 LOGITS (sigmoid monotone) ============
// grid (500, 2), 1024 thr
__global__ void flags_kernel(const double* __restrict__ hm_z,
                             unsigned long long* __restrict__ ballots,
                             unsigned int* __restrict__ counts,
                             vf4* __restrict__ outq)
{
    int b = blockIdx.y;
    int k = blockIdx.x * 1024 + threadIdx.x;

    // zero-fill slice
    {
        const int gtid = (b * NBLK + blockIdx.x) * 1024 + threadIdx.x;
        const vf4 fz = {0.f, 0.f, 0.f, 0.f};
        for (int i = 0; i < 4; i++) {
            long q = QF2 + (long)gtid + (long)i * 1024000;
            if (q < QF3) __builtin_nontemporal_store(fz, outq + q);
        }
    }

    int c = k / NPIX;
    int p = k - c * NPIX;
    int y = p / NXX, xx = p - y * NXX;

    const double* h = hm_z + ((size_t)b * NCLS + c) * NPIX;
    double s = h[p];
    double m = s;
    #pragma unroll
    for (int dy = -1; dy <= 1; dy++) {
        int yy = y + dy;
        if ((unsigned)yy >= (unsigned)NYY) continue;
        const double* hr = h + yy * NXX;
        #pragma unroll
        for (int dx = -1; dx <= 1; dx++) {
            int xn = xx + dx;
            if ((unsigned)xn >= (unsigned)NXX) continue;
            double v = hr[xn];
            m = v > m ? v : m;
        }
    }
    bool flag = (s == m);
    unsigned long long ball = __ballot(flag);
    int lane = threadIdx.x & 63;
    int wave = threadIdx.x >> 6;

    __shared__ unsigned int wcnt[16];
    if (lane == 0) {
        ballots[(size_t)b * 8000 + blockIdx.x * 16 + wave] = ball;
        wcnt[wave] = __popcll(ball);
    }
    __syncthreads();
    if (threadIdx.x == 0) {
        unsigned int tot = 0;
        for (int i = 0; i < 16; i++) tot += wcnt[i];
        counts[b * NBLK + blockIdx.x] = tot;
    }
}

// ============ K4: scatter maxima rows (inline cross-block offset, sigmoid) ============
// grid (500, 2), 1024 thr
__global__ void scatter_kernel(const unsigned long long* __restrict__ ballots,
                               const unsigned int* __restrict__ counts,
                               const double* __restrict__ hm_z,
                               const float* __restrict__ wh,
                               const float* __restrict__ rg,
                               const float* __restrict__ offsets,
                               float* __restrict__ out,
                               vf4* __restrict__ outq)
{
    __shared__ unsigned int csum[512];
    __shared__ unsigned int wc[16];
    __shared__ unsigned int wb[16];
    __shared__ unsigned int sbase;

    int b  = blockIdx.y;
    int bx = blockIdx.x;
    int t  = threadIdx.x;
    int lane = t & 63;
    int wave = t >> 6;

    // zero-fill tail slice (region starts at batch-1 row ~454K >> max rank ~60K)
    {
        const int gtid = (b * NBLK + bx) * 1024 + t;
        const vf4 fz = {0.f, 0.f, 0.f, 0.f};
        for (int i = 0; i < 2; i++) {
            long q = QF3 + (long)gtid + (long)i * 1024000;
            if (q < QTOT) __builtin_nontemporal_store(fz, outq + q);
        }
    }

    if (t < 512) csum[t] = (t < NBLK) ? counts[b * NBLK + t] : 0u;

    unsigned long long ball = ballots[(size_t)b * 8000 + bx * 16 + wave];
    if (lane == 0) wc[wave] = __popcll(ball);
    __syncthreads();

    // cross-block exclusive offset: sum of counts[0..bx-1] via one wave
    if (t < 64) {
        unsigned int s = 0;
        for (int j = t; j < bx; j += 64) s += csum[j];
        #pragma unroll
        for (int d = 32; d >= 1; d >>= 1) s += __shfl_xor(s, d, 64);
        if (t == 0) {
            sbase = s;
            unsigned int a = 0;
            for (int i = 0; i < 16; i++) { wb[i] = a; a += wc[i]; }
        }
    }
    __syncthreads();

    bool flag = (ball >> lane) & 1ull;
    if (!flag) return;

    unsigned int rank = sbase + wb[wave]
                      + (unsigned int)__popcll(ball & ((1ull << lane) - 1ull));

    int k = bx * 1024 + t;
    int c = k / NPIX;
    int p = k - c * NPIX;
    int y = p / NXX, xx = p - y * NXX;

    float offx = offsets[b * 3 + 1];
    float offy = offsets[b * 3 + 2];
    float r0 = rg[((size_t)b * 2 + 0) * NPIX + p];
    float r1 = rg[((size_t)b * 2 + 1) * NPIX + p];
    float w0 = wh[((size_t)b * 2 + 0) * NPIX + p];
    float w1 = wh[((size_t)b * 2 + 1) * NPIX + p];
    double z = hm_z[((size_t)b * NCLS + c) * NPIX + p];
    float s  = (float)(1.0 / (1.0 + exp(-z)));

    float cx = ((float)xx + 2.f * offx + r0) * 4.f;
    float cy = ((float)y  + 2.f * offy + r1) * 4.f;

    float* row = out + ((size_t)b * KTOT + rank) * NOUT;
    row[0] = cx;
    row[1] = cy;
    row[2] = w0 * 4.f;
    row[3] = w1 * 4.f;
    row[4] = s;
    row[5 + c] = 1.f;
}

extern "C" void kernel_launch(void* const* d_in, const int* in_sizes, int n_in,
                              void* d_out, int out_size, void* d_ws, size_t ws_size,
                              hipStream_t stream)
{
    const float* x       = (const float*)d_in[0];
    const float* offsets = (const float*)d_in[1];
    const float* hm_w1   = (const float*)d_in[2];
    const float* hm_b1   = (const float*)d_in[3];
    const float* hm_w2   = (const float*)d_in[4];
    const float* hm_b2   = (const float*)d_in[5];
    const float* wh_w1   = (const float*)d_in[6];
    const float* wh_b1   = (const float*)d_in[7];
    const float* wh_w2   = (const float*)d_in[8];
    const float* wh_b2   = (const float*)d_in[9];
    const float* reg_w1  = (const float*)d_in[10];
    const float* reg_b1  = (const float*)d_in[11];
    const float* reg_w2  = (const float*)d_in[12];
    const float* reg_b2  = (const float*)d_in[13];

    float* out = (float*)d_out;
    vf4* outq  = (vf4*)d_out;

    // workspace layout
    char* wp = (char*)d_ws;
    double* c1hm = (double*)wp;                 wp += (size_t)NBATCH * CHN * NPIX * 8;
    double* hm_z = (double*)wp;                 wp += (size_t)NBATCH * NCLS * NPIX * 8;
    float*  c1wr = (float*)wp;                  wp += (size_t)2 * NBATCH * CHN * NPIX * 4;
    float*  wh   = (float*)wp;                  wp += (size_t)NBATCH * 2 * NPIX * 4;
    float*  rg   = (float*)wp;                  wp += (size_t)NBATCH * 2 * NPIX * 4;
    unsigned long long* ballots = (unsigned long long*)wp; wp += (size_t)NBATCH * 8000 * 8;
    unsigned int* counts = (unsigned int*)wp;

    conv1_kernel<<<480, 320, 0, stream>>>(
        x, hm_w1, hm_b1, wh_w1, wh_b1, reg_w1, reg_b1, c1hm, c1wr, outq);

    conv2_kernel<<<400, 256, 0, stream>>>(
        c1hm, hm_w2, hm_b2, c1wr, wh_w2, wh_b2, reg_w2, reg_b2,
        hm_z, wh, rg, outq);

    flags_kernel<<<dim3(NBLK, 2), 1024, 0, stream>>>(hm_z, ballots, counts, outq);

    scatter_kernel<<<dim3(NBLK, 2), 1024, 0, stream>>>(
        ballots, counts, hm_z, wh, rg, offsets, out, outq);
}

// Round 16
// 147.723 us; speedup vs baseline: 1.0320x; 1.0320x over previous
//
#include <hip/hip_runtime.h>
#include <math.h>

#define NBATCH 2
#define CHN    64
#define NYY    80
#define NXX    80
#define NCLS   80
#define NPIX   6400      // 80*80
#define KTOT   512000    // NCLS*NPIX
#define NOUT   85        // 5 + NCLS
#define NBLK   500       // KTOT / 1024

typedef float vf4 __attribute__((ext_vector_type(4)));

// output = 87,040,000 floats = 21,760,000 float4 quads
#define QTOT   21760000L
#define QF1    16281600L     // conv1: 106 iters x 153600 (75%)
                             // conv2: QF1..QTOT, 54 iters x 102400 guarded (25%)

// ============ K1: fused 3x3 conv + ReLU (hm fp64-acc | wh/reg fp32) ============
// grid 480 x 320 thr, 49,152 B LDS. bl%3==0 -> hm (fp64), else wr (fp32).
__global__ __launch_bounds__(320)
void conv1_kernel(const float* __restrict__ x,
                  const float* __restrict__ hw1, const float* __restrict__ hb1,
                  const float* __restrict__ ww1, const float* __restrict__ wb1,
                  const float* __restrict__ rw1, const float* __restrict__ rb1,
                  double* __restrict__ c1hm, float* __restrict__ c1wr,
                  vf4* __restrict__ outq)
{
    __shared__ double smem_d[6144];    // 49,152 B
    const int bl = blockIdx.x;
    const int t  = threadIdx.x;

    const int gtid = bl * 320 + t;
    const int nth  = 480 * 320;        // 153600
    const vf4 fz = {0.f, 0.f, 0.f, 0.f};

    const int pxq = t % 80;
    const int ocq = t / 80;            // 0..3
    const int r   = pxq / 20;          // row 0..3
    const int c   = (pxq % 20) * 4;    // col 0..76

    float* lxf = (float*)smem_d;       // [16][6][80] floats = 30,720 B

    if (bl % 3 == 0) {
        // ---------------- hm path: fp64 acc ----------------
        double* lwd = (double*)((char*)smem_d + 30720);  // [144][16] = 18,432 B

        const int idx = bl / 3;        // 0..159
        const int yt  = idx % 20;
        const int ocg = (idx / 20) % 4;
        const int b   = idx / 80;
        const int oc0 = ocg * 16 + ocq * 4;
        const int gy0 = yt * 4;

        const float* xin = x + (size_t)b * CHN * NPIX;

        double acc[4][4];
        #pragma unroll
        for (int j = 0; j < 4; j++)
            #pragma unroll
            for (int o = 0; o < 4; o++) acc[j][o] = (double)hb1[oc0 + o];

        for (int cc = 0; cc < 4; cc++) {
            const int icc = cc * 16;
            __syncthreads();
            for (int j = t; j < 1920; j += 320) {
                int ic_l = j / 120; int rem = j % 120;
                int row_l = rem / 20; int c4 = (rem % 20) * 4;
                int gy = gy0 - 1 + row_l;
                float4 v = make_float4(0.f, 0.f, 0.f, 0.f);
                if ((unsigned)gy < 80u)
                    v = *(const float4*)(xin + (size_t)(icc + ic_l) * NPIX + gy * NXX + c4);
                *(float4*)&lxf[(ic_l * 6 + row_l) * 80 + c4] = v;
            }
            for (int j = t; j < 2304; j += 320) {
                int oc_l = j % 16; int k = j / 16;
                int ic_l = k / 9, tap = k % 9;
                lwd[k * 16 + oc_l] =
                    (double)hw1[((size_t)(ocg * 16 + oc_l) * CHN + icc + ic_l) * 9 + tap];
            }
            __syncthreads();
            {   // zero-fill slice: 106 iters total, 27/27/27/25 per phase
                int i0 = cc * 27, i1 = (cc == 3) ? 106 : cc * 27 + 27;
                for (int i = i0; i < i1; i++) {
                    long q = (long)gtid + (long)i * nth;
                    if (q < QF1) __builtin_nontemporal_store(fz, outq + q);
                }
            }
            for (int ic = 0; ic < 16; ic++) {
                double xw[3][6];
                #pragma unroll
                for (int ky = 0; ky < 3; ky++) {
                    const float* row = &lxf[(ic * 6 + r + ky) * 80];
                    xw[ky][0] = (c > 0) ? (double)row[c - 1] : 0.0;
                    float4 m = *(const float4*)&row[c];
                    xw[ky][1] = (double)m.x; xw[ky][2] = (double)m.y;
                    xw[ky][3] = (double)m.z; xw[ky][4] = (double)m.w;
                    xw[ky][5] = (c < 76) ? (double)row[c + 4] : 0.0;
                }
                #pragma unroll
                for (int ky = 0; ky < 3; ky++)
                #pragma unroll
                for (int kx = 0; kx < 3; kx++) {
                    const double* wv = &lwd[(ic * 9 + ky * 3 + kx) * 16 + ocq * 4];
                    double w0 = wv[0], w1d = wv[1], w2 = wv[2], w3 = wv[3];
                    #pragma unroll
                    for (int j = 0; j < 4; j++) {
                        double xv = xw[ky][j + kx];
                        acc[j][0] += xv * w0; acc[j][1] += xv * w1d;
                        acc[j][2] += xv * w2; acc[j][3] += xv * w3;
                    }
                }
            }
        }
        size_t pix = (size_t)(gy0 + r) * NXX + c;
        #pragma unroll
        for (int o = 0; o < 4; o++) {
            double* dst = c1hm + ((size_t)b * CHN + oc0 + o) * NPIX + pix;
            double2 lo, hi;
            lo.x = acc[0][o] > 0.0 ? acc[0][o] : 0.0;
            lo.y = acc[1][o] > 0.0 ? acc[1][o] : 0.0;
            hi.x = acc[2][o] > 0.0 ? acc[2][o] : 0.0;
            hi.y = acc[3][o] > 0.0 ? acc[3][o] : 0.0;
            *(double2*)dst = lo;
            *(double2*)(dst + 2) = hi;
        }
    } else {
        // ---------------- wh/reg path: fp32 ----------------
        float* lwf = (float*)((char*)smem_d + 30720);    // [144][16] = 9,216 B

        const int idx = bl - bl / 3 - 1;   // 0..319
        const int yt  = idx % 20;
        const int ocg = (idx / 20) % 4;
        const int img = idx / 80;          // 0=wh b0, 1=wh b1, 2=reg b0, 3=reg b1

        const int head = img >> 1, b = img & 1;
        const float* w1 = (head == 0) ? ww1 : rw1;
        const float* b1 = (head == 0) ? wb1 : rb1;
        const float* xin = x + (size_t)b * CHN * NPIX;

        const int oc0 = ocg * 16 + ocq * 4;
        const int gy0 = yt * 4;

        float acc[4][4];
        #pragma unroll
        for (int j = 0; j < 4; j++)
            #pragma unroll
            for (int o = 0; o < 4; o++) acc[j][o] = b1[oc0 + o];

        for (int cc = 0; cc < 4; cc++) {
            const int icc = cc * 16;
            __syncthreads();
            for (int j = t; j < 1920; j += 320) {
                int ic_l = j / 120; int rem = j % 120;
                int row_l = rem / 20; int c4 = (rem % 20) * 4;
                int gy = gy0 - 1 + row_l;
                float4 v = make_float4(0.f, 0.f, 0.f, 0.f);
                if ((unsigned)gy < 80u)
                    v = *(const float4*)(xin + (size_t)(icc + ic_l) * NPIX + gy * NXX + c4);
                *(float4*)&lxf[(ic_l * 6 + row_l) * 80 + c4] = v;
            }
            for (int j = t; j < 2304; j += 320) {
                int oc_l = j % 16; int k = j / 16;
                int ic_l = k / 9, tap = k % 9;
                lwf[k * 16 + oc_l] =
                    w1[((size_t)(ocg * 16 + oc_l) * CHN + icc + ic_l) * 9 + tap];
            }
            __syncthreads();
            {
                int i0 = cc * 27, i1 = (cc == 3) ? 106 : cc * 27 + 27;
                for (int i = i0; i < i1; i++) {
                    long q = (long)gtid + (long)i * nth;
                    if (q < QF1) __builtin_nontemporal_store(fz, outq + q);
                }
            }
            for (int ic = 0; ic < 16; ic++) {
                float xw[3][6];
                #pragma unroll
                for (int ky = 0; ky < 3; ky++) {
                    const float* row = &lxf[(ic * 6 + r + ky) * 80];
                    xw[ky][0] = (c > 0) ? row[c - 1] : 0.f;
                    float4 m = *(const float4*)&row[c];
                    xw[ky][1] = m.x; xw[ky][2] = m.y;
                    xw[ky][3] = m.z; xw[ky][4] = m.w;
                    xw[ky][5] = (c < 76) ? row[c + 4] : 0.f;
                }
                #pragma unroll
                for (int ky = 0; ky < 3; ky++)
                #pragma unroll
                for (int kx = 0; kx < 3; kx++) {
                    const float* wv = &lwf[(ic * 9 + ky * 3 + kx) * 16 + ocq * 4];
                    float w0 = wv[0], w1v = wv[1], w2 = wv[2], w3 = wv[3];
                    #pragma unroll
                    for (int j = 0; j < 4; j++) {
                        float xv = xw[ky][j + kx];
                        acc[j][0] += xv * w0; acc[j][1] += xv * w1v;
                        acc[j][2] += xv * w2; acc[j][3] += xv * w3;
                    }
                }
            }
        }
        size_t pix = (size_t)(gy0 + r) * NXX + c;
        #pragma unroll
        for (int o = 0; o < 4; o++) {
            float4 v;
            v.x = fmaxf(acc[0][o], 0.f); v.y = fmaxf(acc[1][o], 0.f);
            v.z = fmaxf(acc[2][o], 0.f); v.w = fmaxf(acc[3][o], 0.f);
            *(float4*)(c1wr + ((size_t)img * CHN + oc0 + o) * NPIX + pix) = v;
        }
    }
}

// ============ K2: merged conv2_hm (fp64 logits, fetch-once) + conv2_wr ============
// grid 400 x 256 thr. bl<200: hm. bl>=200: wr.
__global__ __launch_bounds__(256)
void conv2_kernel(const double* __restrict__ c1hm,
                  const float* __restrict__ hm_w2, const float* __restrict__ hm_b2,
                  const float* __restrict__ c1wr,
                  const float* __restrict__ wh_w2, const float* __restrict__ wh_b2,
                  const float* __restrict__ rg_w2, const float* __restrict__ rg_b2,
                  double* __restrict__ hm_z, float* __restrict__ wh, float* __restrict__ rg,
                  vf4* __restrict__ outq)
{
    __shared__ double smem2[9216];     // 73,728 B (hm path only)
    const int bl = blockIdx.x;
    const int t  = threadIdx.x;

    // zero-fill slice: covers QF1..QTOT (guarded)
    {
        const int gtid = bl * 256 + t;
        const vf4 fz = {0.f, 0.f, 0.f, 0.f};
        for (int i = 0; i < 54; i++) {
            long q = QF1 + (long)gtid + (long)i * 102400;
            if (q < QTOT) __builtin_nontemporal_store(fz, outq + q);
        }
    }

    if (bl < 200) {
        double* lx = smem2;            // [64 ic][64 px] = 32,768 B
        double* lw = smem2 + 4096;     // [64 ic][80 oc] = 40,960 B

        const int b   = bl / 100;
        const int px0 = (bl % 100) * 64;

        const double* in = c1hm + (size_t)b * CHN * NPIX;
        for (int j = t; j < 4096; j += 256) {
            int ic = j >> 6, px = j & 63;
            lx[j] = in[(size_t)ic * NPIX + px0 + px];
        }
        for (int j = t; j < 5120; j += 256) {
            int ic = j / 80, oc = j % 80;
            lw[j] = (double)hm_w2[(size_t)oc * CHN + ic];
        }
        __syncthreads();

        const int px  = t & 63;
        const int ocg = t >> 6;        // 0..3 (wave-uniform -> broadcast reads)
        double acc[20];
        #pragma unroll
        for (int o = 0; o < 20; o++) acc[o] = (double)hm_b2[ocg * 20 + o];

        for (int ic = 0; ic < 64; ic++) {
            double xv = lx[ic * 64 + px];
            const double* wrow = &lw[ic * 80 + ocg * 20];
            #pragma unroll
            for (int o = 0; o < 20; o++) acc[o] += xv * wrow[o];
        }
        #pragma unroll
        for (int o = 0; o < 20; o++)
            hm_z[((size_t)b * NCLS + ocg * 20 + o) * NPIX + px0 + px] = acc[o];
    } else {
        const int blw  = bl - 200;
        const int chunk = blw % 25;
        const int hc   = (blw / 25) % 4;
        const int b    = blw / 100;
        const int head = hc >> 1, ch = hc & 1;

        const int p = chunk * 256 + t;
        const float* in = c1wr + ((size_t)(head * 2 + b) * CHN) * NPIX;
        const float* w  = (head == 0) ? wh_w2 + (size_t)ch * CHN : rg_w2 + (size_t)ch * CHN;
        float acc = (head == 0) ? wh_b2[ch] : rg_b2[ch];
        for (int ic = 0; ic < CHN; ic++) acc += in[(size_t)ic * NPIX + p] * w[ic];
        acc = fmaxf(acc, 0.f);
        float* o = (head == 0) ? wh : rg;
        o[((size_t)b * 2 + ch) * NPIX + p] = acc;
    }
}

// ============ K3: maxima flags on fp64 LOGITS (sigmoid monotone) ============
// grid (500, 2), 1024 thr — no fill (pure compute)
__global__ void flags_kernel(const double* __restrict__ hm_z,
                             unsigned long long* __restrict__ ballots,
                             unsigned int* __restrict__ counts)
{
    int b = blockIdx.y;
    int k = blockIdx.x * 1024 + threadIdx.x;

    int c = k / NPIX;
    int p = k - c * NPIX;
    int y = p / NXX, xx = p - y * NXX;

    const double* h = hm_z + ((size_t)b * NCLS + c) * NPIX;
    double s = h[p];
    double m = s;
    #pragma unroll
    for (int dy = -1; dy <= 1; dy++) {
        int yy = y + dy;
        if ((unsigned)yy >= (unsigned)NYY) continue;
        const double* hr = h + yy * NXX;
        #pragma unroll
        for (int dx = -1; dx <= 1; dx++) {
            int xn = xx + dx;
            if ((unsigned)xn >= (unsigned)NXX) continue;
            double v = hr[xn];
            m = v > m ? v : m;
        }
    }
    bool flag = (s == m);
    unsigned long long ball = __ballot(flag);
    int lane = threadIdx.x & 63;
    int wave = threadIdx.x >> 6;

    __shared__ unsigned int wcnt[16];
    if (lane == 0) {
        ballots[(size_t)b * 8000 + blockIdx.x * 16 + wave] = ball;
        wcnt[wave] = __popcll(ball);
    }
    __syncthreads();
    if (threadIdx.x == 0) {
        unsigned int tot = 0;
        for (int i = 0; i < 16; i++) tot += wcnt[i];
        counts[b * NBLK + blockIdx.x] = tot;
    }
}

// ============ K4: scatter maxima rows (inline cross-block offset, sigmoid) ============
// grid (500, 2), 1024 thr — no fill (pure scatter)
__global__ void scatter_kernel(const unsigned long long* __restrict__ ballots,
                               const unsigned int* __restrict__ counts,
                               const double* __restrict__ hm_z,
                               const float* __restrict__ wh,
                               const float* __restrict__ rg,
                               const float* __restrict__ offsets,
                               float* __restrict__ out)
{
    __shared__ unsigned int csum[512];
    __shared__ unsigned int wc[16];
    __shared__ unsigned int wb[16];
    __shared__ unsigned int sbase;

    int b  = blockIdx.y;
    int bx = blockIdx.x;
    int t  = threadIdx.x;
    int lane = t & 63;
    int wave = t >> 6;

    if (t < 512) csum[t] = (t < NBLK) ? counts[b * NBLK + t] : 0u;

    unsigned long long ball = ballots[(size_t)b * 8000 + bx * 16 + wave];
    if (lane == 0) wc[wave] = __popcll(ball);
    __syncthreads();

    // cross-block exclusive offset: sum of counts[0..bx-1] via one wave
    if (t < 64) {
        unsigned int s = 0;
        for (int j = t; j < bx; j += 64) s += csum[j];
        #pragma unroll
        for (int d = 32; d >= 1; d >>= 1) s += __shfl_xor(s, d, 64);
        if (t == 0) {
            sbase = s;
            unsigned int a = 0;
            for (int i = 0; i < 16; i++) { wb[i] = a; a += wc[i]; }
        }
    }
    __syncthreads();

    bool flag = (ball >> lane) & 1ull;
    if (!flag) return;

    unsigned int rank = sbase + wb[wave]
                      + (unsigned int)__popcll(ball & ((1ull << lane) - 1ull));

    int k = bx * 1024 + t;
    int c = k / NPIX;
    int p = k - c * NPIX;
    int y = p / NXX, xx = p - y * NXX;

    float offx = offsets[b * 3 + 1];
    float offy = offsets[b * 3 + 2];
    float r0 = rg[((size_t)b * 2 + 0) * NPIX + p];
    float r1 = rg[((size_t)b * 2 + 1) * NPIX + p];
    float w0 = wh[((size_t)b * 2 + 0) * NPIX + p];
    float w1 = wh[((size_t)b * 2 + 1) * NPIX + p];
    double z = hm_z[((size_t)b * NCLS + c) * NPIX + p];
    float s  = (float)(1.0 / (1.0 + exp(-z)));

    float cx = ((float)xx + 2.f * offx + r0) * 4.f;
    float cy = ((float)y  + 2.f * offy + r1) * 4.f;

    float* row = out + ((size_t)b * KTOT + rank) * NOUT;
    row[0] = cx;
    row[1] = cy;
    row[2] = w0 * 4.f;
    row[3] = w1 * 4.f;
    row[4] = s;
    row[5 + c] = 1.f;
}

extern "C" void kernel_launch(void* const* d_in, const int* in_sizes, int n_in,
                              void* d_out, int out_size, void* d_ws, size_t ws_size,
                              hipStream_t stream)
{
    const float* x       = (const float*)d_in[0];
    const float* offsets = (const float*)d_in[1];
    const float* hm_w1   = (const float*)d_in[2];
    const float* hm_b1   = (const float*)d_in[3];
    const float* hm_w2   = (const float*)d_in[4];
    const float* hm_b2   = (const float*)d_in[5];
    const float* wh_w1   = (const float*)d_in[6];
    const float* wh_b1   = (const float*)d_in[7];
    const float* wh_w2   = (const float*)d_in[8];
    const float* wh_b2   = (const float*)d_in[9];
    const float* reg_w1  = (const float*)d_in[10];
    const float* reg_b1  = (const float*)d_in[11];
    const float* reg_w2  = (const float*)d_in[12];
    const float* reg_b2  = (const float*)d_in[13];

    float* out = (float*)d_out;
    vf4* outq  = (vf4*)d_out;

    // workspace layout
    char* wp = (char*)d_ws;
    double* c1hm = (double*)wp;                 wp += (size_t)NBATCH * CHN * NPIX * 8;
    double* hm_z = (double*)wp;                 wp += (size_t)NBATCH * NCLS * NPIX * 8;
    float*  c1wr = (float*)wp;                  wp += (size_t)2 * NBATCH * CHN * NPIX * 4;
    float*  wh   = (float*)wp;                  wp += (size_t)NBATCH * 2 * NPIX * 4;
    float*  rg   = (float*)wp;                  wp += (size_t)NBATCH * 2 * NPIX * 4;
    unsigned long long* ballots = (unsigned long long*)wp; wp += (size_t)NBATCH * 8000 * 8;
    unsigned int* counts = (unsigned int*)wp;

    conv1_kernel<<<480, 320, 0, stream>>>(
        x, hm_w1, hm_b1, wh_w1, wh_b1, reg_w1, reg_b1, c1hm, c1wr, outq);

    conv2_kernel<<<400, 256, 0, stream>>>(
        c1hm, hm_w2, hm_b2, c1wr, wh_w2, wh_b2, reg_w2, reg_b2,
        hm_z, wh, rg, outq);

    flags_kernel<<<dim3(NBLK, 2), 1024, 0, stream>>>(hm_z, ballots, counts);

    scatter_kernel<<<dim3(NBLK, 2), 1024, 0, stream>>>(
        ballots, counts, hm_z, wh, rg, offsets, out);
}